// Round 1
// baseline (227.449 us; speedup 1.0000x reference)
//
#include <hip/hip_runtime.h>

#define N_ROWS 32768
#define D 128
#define K_EMB 1024
#define BM 64
#define BN 64
#define LDX 132           // padded stride: 16B-aligned float4, 2-way bank alias (free)
#define NCHUNK (K_EMB / BN)

__global__ __launch_bounds__(256) void vq_prep(const float* __restrict__ emb,
                                               float* __restrict__ enorm,
                                               float* __restrict__ loss_slot) {
    int t = blockIdx.x * 256 + threadIdx.x;   // 16384 threads, 16 lanes per row
    int row = t >> 4;
    int part = t & 15;
    const float4* e4 = (const float4*)(emb + (size_t)row * D);
    float4 u = e4[part * 2];
    float4 w = e4[part * 2 + 1];
    float s = u.x*u.x + u.y*u.y + u.z*u.z + u.w*u.w
            + w.x*w.x + w.y*w.y + w.z*w.z + w.w*w.w;
    #pragma unroll
    for (int off = 8; off; off >>= 1) s += __shfl_down(s, off, 16);
    if (part == 0) enorm[row] = s;
    if (t == 0) *loss_slot = 0.0f;            // d_out is poisoned 0xAA every call
}

__global__ __launch_bounds__(256) void vq_main(const float* __restrict__ x,
                                               const float* __restrict__ emb,
                                               const float* __restrict__ enorm,
                                               float* __restrict__ outq,
                                               float* __restrict__ loss_slot) {
    __shared__ float Xs[BM][LDX];
    __shared__ float Es[BN][LDX];
    __shared__ float En[BN];
    __shared__ int   rowidx[BM];
    __shared__ float lsum[4];

    const int t = threadIdx.x;
    const int b = blockIdx.x;
    const size_t row0 = (size_t)b * BM;

    // ---- stage X tile (64 rows x 128 floats), coalesced float4 ----
    {
        const float4* src = (const float4*)(x + row0 * D);
        #pragma unroll
        for (int i = 0; i < 8; ++i) {
            int f4 = t + i * 256;         // 0..2047
            int r  = f4 >> 5;
            int c4 = f4 & 31;
            float4 v = src[f4];
            *(float4*)&Xs[r][c4 * 4] = v;
        }
    }

    const int tr = t >> 4;     // row group 0..15
    const int tc = t & 15;     // col group 0..15
    const int r0 = tr * 4;

    float minv[4];
    int   mini[4];
    #pragma unroll
    for (int i = 0; i < 4; ++i) { minv[i] = 3.0e38f; mini[i] = 0; }

    for (int ch = 0; ch < NCHUNK; ++ch) {
        __syncthreads();   // previous-chunk compute done (also guards Xs on ch=0)
        {
            const float4* src = (const float4*)(emb + (size_t)(ch * BN) * D);
            #pragma unroll
            for (int i = 0; i < 8; ++i) {
                int f4 = t + i * 256;
                int r  = f4 >> 5;
                int c4 = f4 & 31;
                float4 v = src[f4];
                *(float4*)&Es[r][c4 * 4] = v;
            }
            if (t < BN) En[t] = enorm[ch * BN + t];
        }
        __syncthreads();

        float acc[4][4];
        #pragma unroll
        for (int i = 0; i < 4; ++i)
            #pragma unroll
            for (int j = 0; j < 4; ++j) acc[i][j] = 0.0f;

        // 64 FMA per 8 ds_read_b128; cols strided by 16 so b-reads are 2-way max
        #pragma unroll 8
        for (int d4 = 0; d4 < 32; ++d4) {
            float4 a[4], bb[4];
            #pragma unroll
            for (int i = 0; i < 4; ++i) a[i]  = *(const float4*)&Xs[r0 + i][d4 * 4];
            #pragma unroll
            for (int j = 0; j < 4; ++j) bb[j] = *(const float4*)&Es[tc + 16 * j][d4 * 4];
            #pragma unroll
            for (int i = 0; i < 4; ++i)
                #pragma unroll
                for (int j = 0; j < 4; ++j)
                    acc[i][j] += a[i].x * bb[j].x + a[i].y * bb[j].y
                               + a[i].z * bb[j].z + a[i].w * bb[j].w;
        }

        // score = ||e||^2 - 2 x.e  (||x||^2 constant per row, irrelevant to argmin)
        #pragma unroll
        for (int j = 0; j < 4; ++j) {
            int c = tc + 16 * j;
            float en = En[c];
            int gidx = ch * BN + c;
            #pragma unroll
            for (int i = 0; i < 4; ++i) {
                float s = en - 2.0f * acc[i][j];
                if (s < minv[i]) { minv[i] = s; mini[i] = gidx; }
            }
        }
    }

    // ---- reduce (min,idx) across the 16 col-group lanes (within one wave) ----
    #pragma unroll
    for (int i = 0; i < 4; ++i) {
        float v = minv[i];
        int  ii = mini[i];
        #pragma unroll
        for (int off = 8; off; off >>= 1) {
            float ov = __shfl_down(v, off, 16);
            int   oi = __shfl_down(ii, off, 16);
            if (ov < v || (ov == v && oi < ii)) { v = ov; ii = oi; }  // np tie-break: lowest idx
        }
        if (tc == 0) rowidx[r0 + i] = ii;
    }
    __syncthreads();

    // ---- epilogue: gather q, write out, accumulate loss = 1.5 * sum (q-x)^2 ----
    const int erow  = t >> 2;   // 4 threads per row
    const int epart = t & 3;
    const int gi = rowidx[erow];
    const float* esrc = emb + (size_t)gi * D;
    float* dst = outq + (row0 + erow) * D;
    float lacc = 0.0f;
    #pragma unroll
    for (int jj = 0; jj < 8; ++jj) {
        int c = epart * 4 + jj * 16;
        float4 e  = *(const float4*)(esrc + c);
        float4 xv = *(const float4*)&Xs[erow][c];
        float dx = e.x - xv.x, dy = e.y - xv.y, dz = e.z - xv.z, dw = e.w - xv.w;
        lacc += dx * dx + dy * dy + dz * dz + dw * dw;
        *(float4*)(dst + c) = e;
    }
    #pragma unroll
    for (int off = 32; off; off >>= 1) lacc += __shfl_down(lacc, off, 64);
    if ((t & 63) == 0) lsum[t >> 6] = lacc;
    __syncthreads();
    if (t == 0) {
        float bs = (lsum[0] + lsum[1]) + (lsum[2] + lsum[3]);
        atomicAdd(loss_slot, 1.5f * bs);
    }
}

extern "C" void kernel_launch(void* const* d_in, const int* in_sizes, int n_in,
                              void* d_out, int out_size, void* d_ws, size_t ws_size,
                              hipStream_t stream) {
    const float* x   = (const float*)d_in[0];   // inputs [32,32,32,128] -> [32768,128]
    const float* emb = (const float*)d_in[1];   // embeddings [1024,128]
    float* outq      = (float*)d_out;
    float* loss_slot = outq + (size_t)N_ROWS * D;
    float* enorm     = (float*)d_ws;            // 1024 floats of scratch

    vq_prep<<<(K_EMB * 16) / 256, 256, 0, stream>>>(emb, enorm, loss_slot);
    vq_main<<<N_ROWS / BM, 256, 0, stream>>>(x, emb, enorm, outq, loss_slot);
}

// Round 2
// 160.546 us; speedup vs baseline: 1.4167x; 1.4167x over previous
//
#include <hip/hip_runtime.h>

typedef __attribute__((ext_vector_type(8))) short short8;
typedef __attribute__((ext_vector_type(4))) float f32x4;

#define N_ROWS 32768
#define D 128
#define K_EMB 1024

// ws byte layout
#define WS_EHI 0
#define WS_ELO (K_EMB * D * 2)            // 262144
#define WS_EN  (WS_ELO + K_EMB * D * 2)   // 524288
#define WS_TOP (WS_EN + K_EMB * 4)        // 528384  (int2 per row per half = 512 KB)

__device__ __forceinline__ unsigned short f2bf(float f) {
    unsigned u = __float_as_uint(f);
    u += 0x7fffu + ((u >> 16) & 1u);      // RNE to bf16
    return (unsigned short)(u >> 16);
}

// ---- prep: emb -> Ehi/Elo bf16 split + enorm(fp32) ; zero loss slot ----
__global__ __launch_bounds__(256) void vq_prep(const float* __restrict__ emb,
                                               unsigned short* __restrict__ Ehi,
                                               unsigned short* __restrict__ Elo,
                                               float* __restrict__ enorm,
                                               float* __restrict__ loss_slot) {
    int t = blockIdx.x * 256 + threadIdx.x;  // 16384 threads: 1024 rows x 16 lanes
    int row = t >> 4, part = t & 15;
    const float4* e4 = (const float4*)(emb + (size_t)row * D);
    float4 a = e4[part * 2], b = e4[part * 2 + 1];
    float xv[8] = {a.x, a.y, a.z, a.w, b.x, b.y, b.z, b.w};
    short8 sh, sl;
    float s = 0.0f;
    #pragma unroll
    for (int j = 0; j < 8; ++j) {
        float f = xv[j];
        s += f * f;
        unsigned short hb = f2bf(f);
        float hf = __uint_as_float(((unsigned)hb) << 16);
        unsigned short lb = f2bf(f - hf);
        sh[j] = (short)hb;
        sl[j] = (short)lb;
    }
    *(short8*)(Ehi + (size_t)row * D + part * 8) = sh;
    *(short8*)(Elo + (size_t)row * D + part * 8) = sl;
    #pragma unroll
    for (int off = 8; off; off >>= 1) s += __shfl_down(s, off, 16);
    if (part == 0) enorm[row] = s;
    if (t == 0) *loss_slot = 0.0f;           // d_out is re-poisoned every call
}

// ---- main: split-bf16 MFMA distances + per-row top-2 per column-half ----
// grid: 512 blocks = 256 row-groups (128 rows) x 2 halves (512 cols each)
// block: 256 thr = 4 waves x 32 rows; X frags register-resident; LDS streams E.
__global__ __launch_bounds__(256) void vq_main(const float* __restrict__ x,
                                               const unsigned short* __restrict__ Ehi,
                                               const unsigned short* __restrict__ Elo,
                                               const float* __restrict__ enorm,
                                               int2* __restrict__ wsTop) {
    __shared__ unsigned short sEhi[128 * 136];  // stride 136: conflict-free b128
    __shared__ unsigned short sElo[128 * 136];
    __shared__ float sEn[128];

    const int t = threadIdx.x;
    const int bid = blockIdx.x;
    const int rowgrp = bid >> 1;
    const int h = bid & 1;
    const int wave = t >> 6;
    const int lane = t & 63;
    const int l15 = lane & 15;
    const int quad = lane >> 4;
    const int rbase = rowgrp * 128 + wave * 32;
    const int hbase = h * 512;

    // A fragments (hi/lo) for 2 row-tiles x 4 k-chunks, register-resident
    short8 ahi[2][4], alo[2][4];
    #pragma unroll
    for (int rt = 0; rt < 2; ++rt)
        #pragma unroll
        for (int kc = 0; kc < 4; ++kc) {
            const float* src = x + (size_t)(rbase + rt * 16 + l15) * D + kc * 32 + quad * 8;
            float4 a = *(const float4*)src;
            float4 b = *(const float4*)(src + 4);
            float xv[8] = {a.x, a.y, a.z, a.w, b.x, b.y, b.z, b.w};
            short8 sh, sl;
            #pragma unroll
            for (int j = 0; j < 8; ++j) {
                float f = xv[j];
                unsigned short hb = f2bf(f);
                float hf = __uint_as_float(((unsigned)hb) << 16);
                sh[j] = (short)hb;
                sl[j] = (short)f2bf(f - hf);
            }
            ahi[rt][kc] = sh;
            alo[rt][kc] = sl;
        }

    // per-lane top-2 for 8 rows (2 rt x 4 reg)
    float v1[8], v2[8];
    int   i1[8], i2[8];
    #pragma unroll
    for (int s = 0; s < 8; ++s) { v1[s] = 3.0e38f; v2[s] = 3.0e38f; i1[s] = 0; i2[s] = 0; }

    for (int ch = 0; ch < 4; ++ch) {
        __syncthreads();
        {   // stage 128 embeddings (hi+lo) into padded LDS
            const int4* ghi = (const int4*)(Ehi + (size_t)(hbase + ch * 128) * D);
            const int4* glo = (const int4*)(Elo + (size_t)(hbase + ch * 128) * D);
            #pragma unroll
            for (int i = 0; i < 8; ++i) {
                int idx = t + i * 256;          // 0..2047 int4s (16 per row)
                int r = idx >> 4, c = idx & 15;
                *(int4*)&sEhi[r * 136 + c * 8] = ghi[idx];
                *(int4*)&sElo[r * 136 + c * 8] = glo[idx];
            }
            if (t < 128) sEn[t] = enorm[hbase + ch * 128 + t];
        }
        __syncthreads();

        for (int ct = 0; ct < 8; ++ct) {
            short8 bhi[4], blo[4];
            #pragma unroll
            for (int kc = 0; kc < 4; ++kc) {
                int off = (ct * 16 + l15) * 136 + kc * 32 + quad * 8;
                bhi[kc] = *(const short8*)&sEhi[off];
                blo[kc] = *(const short8*)&sElo[off];
            }
            f32x4 acc[2] = {{0.f, 0.f, 0.f, 0.f}, {0.f, 0.f, 0.f, 0.f}};
            #pragma unroll
            for (int rt = 0; rt < 2; ++rt)
                #pragma unroll
                for (int kc = 0; kc < 4; ++kc) {
                    acc[rt] = __builtin_amdgcn_mfma_f32_16x16x32_bf16(ahi[rt][kc], bhi[kc], acc[rt], 0, 0, 0);
                    acc[rt] = __builtin_amdgcn_mfma_f32_16x16x32_bf16(ahi[rt][kc], blo[kc], acc[rt], 0, 0, 0);
                    acc[rt] = __builtin_amdgcn_mfma_f32_16x16x32_bf16(alo[rt][kc], bhi[kc], acc[rt], 0, 0, 0);
                }
            float en = sEn[ct * 16 + l15];
            int gcol = hbase + ch * 128 + ct * 16 + l15;
            #pragma unroll
            for (int rt = 0; rt < 2; ++rt)
                #pragma unroll
                for (int r = 0; r < 4; ++r) {
                    float s = en - 2.0f * acc[rt][r];
                    int slot = rt * 4 + r;
                    if (s < v1[slot]) {
                        v2[slot] = v1[slot]; i2[slot] = i1[slot];
                        v1[slot] = s;        i1[slot] = gcol;
                    } else if (s < v2[slot]) {
                        v2[slot] = s;        i2[slot] = gcol;
                    }
                }
        }
    }

    // merge top-2 across the 16 lanes of each quad (same row)
    #pragma unroll
    for (int slot = 0; slot < 8; ++slot) {
        float a1 = v1[slot], a2 = v2[slot];
        int   b1 = i1[slot], b2 = i2[slot];
        #pragma unroll
        for (int m = 1; m < 16; m <<= 1) {
            float w1 = __shfl_xor(a1, m, 16); int j1 = __shfl_xor(b1, m, 16);
            float w2 = __shfl_xor(a2, m, 16); int j2 = __shfl_xor(b2, m, 16);
            bool wb = (w1 < a1) || (w1 == a1 && j1 < b1);
            if (wb) {
                bool s2 = (a1 < w2) || (a1 == w2 && b1 < j2);
                a2 = s2 ? a1 : w2; b2 = s2 ? b1 : j2;
                a1 = w1; b1 = j1;
            } else {
                bool s2 = (w1 < a2) || (w1 == a2 && j1 < b2);
                a2 = s2 ? w1 : a2; b2 = s2 ? j1 : b2;
            }
        }
        if (l15 == 0) {
            int row = rbase + (slot >> 2) * 16 + quad * 4 + (slot & 3);
            wsTop[row * 2 + h] = make_int2(b1, b2);
        }
    }
}

// ---- epilogue: exact fp32 recheck of <=4 candidates, gather q, loss ----
__global__ __launch_bounds__(256) void vq_epilogue(const float* __restrict__ x,
                                                   const float* __restrict__ emb,
                                                   const int2* __restrict__ wsTop,
                                                   float* __restrict__ outq,
                                                   float* __restrict__ loss_slot) {
    __shared__ float lsum[4];
    const int t = threadIdx.x;
    const int row = blockIdx.x * 16 + (t >> 4);   // 16 rows/block, 16 lanes/row
    const int l = t & 15;

    int2 c01 = wsTop[row * 2];
    int2 c23 = wsTop[row * 2 + 1];
    int cidx[4] = {c01.x, c01.y, c23.x, c23.y};

    const float* xp = x + (size_t)row * D + l * 8;
    float4 x0 = *(const float4*)xp;
    float4 x1 = *(const float4*)(xp + 4);

    float d[4];
    #pragma unroll
    for (int c = 0; c < 4; ++c) {
        const float* ep = emb + (size_t)cidx[c] * D + l * 8;
        float4 e0 = *(const float4*)ep;
        float4 e1 = *(const float4*)(ep + 4);
        float dx = x0.x - e0.x, dy = x0.y - e0.y, dz = x0.z - e0.z, dw = x0.w - e0.w;
        float s = dx * dx + dy * dy + dz * dz + dw * dw;
        dx = x1.x - e1.x; dy = x1.y - e1.y; dz = x1.z - e1.z; dw = x1.w - e1.w;
        s += dx * dx + dy * dy + dz * dz + dw * dw;
        #pragma unroll
        for (int off = 8; off; off >>= 1) s += __shfl_xor(s, off, 16);  // all lanes get total
        d[c] = s;
    }

    // all 16 lanes agree on the winner (np tie-break: lowest index)
    float bd = d[0]; int bi = cidx[0];
    #pragma unroll
    for (int c = 1; c < 4; ++c)
        if (d[c] < bd || (d[c] == bd && cidx[c] < bi)) { bd = d[c]; bi = cidx[c]; }

    // gather q (exact embedding row, L1-hot) and write
    const float* ep = emb + (size_t)bi * D + l * 8;
    float4 q0 = *(const float4*)ep;
    float4 q1 = *(const float4*)(ep + 4);
    float* dst = outq + (size_t)row * D + l * 8;
    *(float4*)dst = q0;
    *(float4*)(dst + 4) = q1;

    // loss = 1.5 * sum(best d); one contribution per row (lane 0)
    float lacc = (l == 0) ? bd : 0.0f;
    #pragma unroll
    for (int off = 32; off; off >>= 1) lacc += __shfl_down(lacc, off, 64);
    if ((t & 63) == 0) lsum[t >> 6] = lacc;
    __syncthreads();
    if (t == 0) {
        float bs = (lsum[0] + lsum[1]) + (lsum[2] + lsum[3]);
        atomicAdd(loss_slot, 1.5f * bs);
    }
}

extern "C" void kernel_launch(void* const* d_in, const int* in_sizes, int n_in,
                              void* d_out, int out_size, void* d_ws, size_t ws_size,
                              hipStream_t stream) {
    const float* x   = (const float*)d_in[0];   // [32768,128]
    const float* emb = (const float*)d_in[1];   // [1024,128]
    float* outq      = (float*)d_out;
    float* loss_slot = outq + (size_t)N_ROWS * D;

    char* ws = (char*)d_ws;
    unsigned short* Ehi = (unsigned short*)(ws + WS_EHI);
    unsigned short* Elo = (unsigned short*)(ws + WS_ELO);
    float* enorm        = (float*)(ws + WS_EN);
    int2* wsTop         = (int2*)(ws + WS_TOP);

    vq_prep<<<64, 256, 0, stream>>>(emb, Ehi, Elo, enorm, loss_slot);
    vq_main<<<512, 256, 0, stream>>>(x, Ehi, Elo, enorm, wsTop);
    vq_epilogue<<<N_ROWS / 16, 256, 0, stream>>>(x, emb, wsTop, outq, loss_slot);
}

// Round 3
// 112.432 us; speedup vs baseline: 2.0230x; 1.4279x over previous
//
#include <hip/hip_runtime.h>

typedef __attribute__((ext_vector_type(8))) short short8;
typedef __attribute__((ext_vector_type(4))) float f32x4;

#define N_ROWS 32768
#define D 128
#define K_EMB 1024

// ws byte layout (all 16B-aligned)
#define WS_EHI 0                           // 256 KB, fragment-permuted bf16 hi
#define WS_ELO (K_EMB * D * 2)             // 256 KB, fragment-permuted bf16 lo
#define WS_EN  (WS_ELO + K_EMB * D * 2)    // 4 KB, ||e||^2 * 1024

__device__ __forceinline__ unsigned short f2bf(float f) {
    unsigned u = __float_as_uint(f);
    u += 0x7fffu + ((u >> 16) & 1u);       // RNE to bf16
    return (unsigned short)(u >> 16);
}

// ---- prep: emb -> fragment-permuted Ehi/Elo + 1024*||e||^2 ; zero loss ----
// frag linear index within a 128-col chunk: ((ct*4+kc)*4+quad)*16 + l15
// frag contents: E[col = chunk*128 + ct*16 + l15][dims kc*32+quad*8 .. +8]
__global__ __launch_bounds__(256) void vq_prep(const float* __restrict__ emb,
                                               short8* __restrict__ Ehi,
                                               short8* __restrict__ Elo,
                                               float* __restrict__ en1024,
                                               float* __restrict__ loss_slot) {
    int t = blockIdx.x * 256 + threadIdx.x;   // 16384: 1024 cols x 16 parts
    int col = t >> 4, part = t & 15;
    int kc = part >> 2, quad = part & 3;
    int chunk = col >> 7, cc = col & 127;
    int ct = cc >> 4, l15 = cc & 15;

    const float4* e4 = (const float4*)(emb + (size_t)col * D + part * 8);
    float4 a = e4[0], b = e4[1];
    float xv[8] = {a.x, a.y, a.z, a.w, b.x, b.y, b.z, b.w};
    short8 sh, sl;
    float s = 0.0f;
    #pragma unroll
    for (int j = 0; j < 8; ++j) {
        float f = xv[j];
        s += f * f;
        unsigned short hb = f2bf(f);
        float hf = __uint_as_float(((unsigned)hb) << 16);
        sh[j] = (short)hb;
        sl[j] = (short)f2bf(f - hf);
    }
    int fi = chunk * 2048 + ((ct * 4 + kc) * 4 + quad) * 16 + l15;
    Ehi[fi] = sh;
    Elo[fi] = sl;
    #pragma unroll
    for (int off = 8; off; off >>= 1) s += __shfl_down(s, off, 16);
    if (part == 0) en1024[col] = s * 1024.0f;
    if (t == 0) *loss_slot = 0.0f;
}

// ---- main: fused distances + argmin + exact recheck + gather + loss ----
// grid 256 (1 block/CU), block 256 = 4 waves x 32 rows; full K=1024 per block.
__global__ __launch_bounds__(256, 1) void vq_main(const float* __restrict__ x,
                                                  const int4* __restrict__ EhiV,
                                                  const int4* __restrict__ EloV,
                                                  const float* __restrict__ en1024,
                                                  const float* __restrict__ emb,
                                                  float* __restrict__ outq,
                                                  float* __restrict__ loss_slot) {
    __shared__ int4  sB[2][2][2048];   // [buf][hi/lo][frag] = 128 KB
    __shared__ float sEn[K_EMB];       // 4 KB
    __shared__ int2  sTop[128];
    __shared__ float lsum[4];

    const int t = threadIdx.x;
    const int wave = t >> 6;
    const int lane = t & 63;
    const int l15 = lane & 15;
    const int quad = lane >> 4;
    const int rbase = blockIdx.x * 128 + wave * 32;

    // preload en (1024 floats) once
    ((float4*)sEn)[t] = ((const float4*)en1024)[t];

    // stage chunk 0 into buf 0
    #pragma unroll
    for (int p = 0; p < 8; ++p) {
        int idx = p * 256 + t;
        sB[0][0][idx] = EhiV[idx];
        sB[0][1][idx] = EloV[idx];
    }

    // A fragments: 32 rows/wave (2 row-tiles), bf16 hi/lo, register-resident
    short8 ahi[2][4], alo[2][4];
    #pragma unroll
    for (int rt = 0; rt < 2; ++rt)
        #pragma unroll
        for (int kc = 0; kc < 4; ++kc) {
            const float* src = x + (size_t)(rbase + rt * 16 + l15) * D + kc * 32 + quad * 8;
            float4 a = *(const float4*)src;
            float4 b = *(const float4*)(src + 4);
            float xv[8] = {a.x, a.y, a.z, a.w, b.x, b.y, b.z, b.w};
            short8 sh, sl;
            #pragma unroll
            for (int j = 0; j < 8; ++j) {
                float f = xv[j];
                unsigned short hb = f2bf(f);
                float hf = __uint_as_float(((unsigned)hb) << 16);
                sh[j] = (short)hb;
                sl[j] = (short)f2bf(f - hf);
            }
            ahi[rt][kc] = sh;
            alo[rt][kc] = sl;
        }

    // packed top-2 keys per slot (8 slots = 2rt x 4 acc-regs)
    int k1[8], k2[8];
    #pragma unroll
    for (int s = 0; s < 8; ++s) { k1[s] = 0x7fffffff; k2[s] = 0x7fffffff; }

    for (int ch = 0; ch < 8; ++ch) {
        const int cur = ch & 1;
        __syncthreads();                      // cur buffer's staging complete
        if (ch < 7) {                         // prefetch next chunk into other buf
            const int4* gh = EhiV + (ch + 1) * 2048;
            const int4* gl = EloV + (ch + 1) * 2048;
            #pragma unroll
            for (int p = 0; p < 8; ++p) {
                int idx = p * 256 + t;
                sB[cur ^ 1][0][idx] = gh[idx];
                sB[cur ^ 1][1][idx] = gl[idx];
            }
        }
        #pragma unroll
        for (int pr = 0; pr < 4; ++pr) {      // 2 col-tiles (32 cols) per pass
            short8 bh[2][4], bl[2][4];
            #pragma unroll
            for (int c2 = 0; c2 < 2; ++c2)
                #pragma unroll
                for (int kc = 0; kc < 4; ++kc) {
                    int fi = (((pr * 2 + c2) * 4 + kc) * 4 + quad) * 16 + l15;
                    bh[c2][kc] = *(const short8*)&sB[cur][0][fi];
                    bl[c2][kc] = *(const short8*)&sB[cur][1][fi];
                }
            f32x4 acc[2][2] = {{{0.f,0.f,0.f,0.f},{0.f,0.f,0.f,0.f}},
                               {{0.f,0.f,0.f,0.f},{0.f,0.f,0.f,0.f}}};
            #pragma unroll
            for (int kc = 0; kc < 4; ++kc)
                #pragma unroll
                for (int rt = 0; rt < 2; ++rt)
                    #pragma unroll
                    for (int c2 = 0; c2 < 2; ++c2) {
                        acc[rt][c2] = __builtin_amdgcn_mfma_f32_16x16x32_bf16(ahi[rt][kc], bh[c2][kc], acc[rt][c2], 0, 0, 0);
                        acc[rt][c2] = __builtin_amdgcn_mfma_f32_16x16x32_bf16(ahi[rt][kc], bl[c2][kc], acc[rt][c2], 0, 0, 0);
                        acc[rt][c2] = __builtin_amdgcn_mfma_f32_16x16x32_bf16(alo[rt][kc], bh[c2][kc], acc[rt][c2], 0, 0, 0);
                    }
            #pragma unroll
            for (int c2 = 0; c2 < 2; ++c2) {
                int col = ch * 128 + (pr * 2 + c2) * 16 + l15;
                float enk = sEn[col];
                #pragma unroll
                for (int rt = 0; rt < 2; ++rt)
                    #pragma unroll
                    for (int r = 0; r < 4; ++r) {
                        int kk = (int)(enk - 2048.0f * acc[rt][c2][r]);  // trunc: monotone
                        int key = (kk << 10) + col;                      // np tie-break in low bits
                        int s = rt * 4 + r;
                        int mx = k1[s] > key ? k1[s] : key;
                        k1[s] = k1[s] < key ? k1[s] : key;
                        k2[s] = k2[s] < mx ? k2[s] : mx;
                    }
            }
        }
    }

    // merge top-2 across the 16 lanes of each quad-row
    #pragma unroll
    for (int s = 0; s < 8; ++s) {
        int a1 = k1[s], a2 = k2[s];
        #pragma unroll
        for (int m = 1; m < 16; m <<= 1) {
            int o1 = __shfl_xor(a1, m, 16);
            int o2 = __shfl_xor(a2, m, 16);
            int mx  = a1 > o1 ? a1 : o1;
            a1      = a1 < o1 ? a1 : o1;
            int mn2 = a2 < o2 ? a2 : o2;
            a2      = mx < mn2 ? mx : mn2;
        }
        if (l15 == 0) {
            int rib = wave * 32 + (s >> 2) * 16 + quad * 4 + (s & 3);
            sTop[rib] = make_int2(a1, a2);
        }
    }
    __syncthreads();

    // fused epilogue: exact fp32 recheck of 2 candidates, gather q, loss
    float lacc = 0.0f;
    #pragma unroll
    for (int rep = 0; rep < 4; ++rep) {
        int rib = rep * 32 + (t >> 3);        // 32 rows per pass, 8 lanes/row
        int l8 = t & 7;
        size_t row = (size_t)blockIdx.x * 128 + rib;
        int2 tp = sTop[rib];
        int c1 = tp.x & 1023, c2 = tp.y & 1023;

        const float4* xp = (const float4*)(x + row * D + l8 * 16);
        float4 xv0 = xp[0], xv1 = xp[1], xv2 = xp[2], xv3 = xp[3];

        const float4* e1p = (const float4*)(emb + (size_t)c1 * D + l8 * 16);
        const float4* e2p = (const float4*)(emb + (size_t)c2 * D + l8 * 16);
        float4 e1[4] = {e1p[0], e1p[1], e1p[2], e1p[3]};
        float4 e2[4] = {e2p[0], e2p[1], e2p[2], e2p[3]};
        float4 xs[4] = {xv0, xv1, xv2, xv3};
        float d1 = 0.f, d2 = 0.f;
        #pragma unroll
        for (int j = 0; j < 4; ++j) {
            float dx = e1[j].x - xs[j].x, dy = e1[j].y - xs[j].y,
                  dz = e1[j].z - xs[j].z, dw = e1[j].w - xs[j].w;
            d1 += dx * dx + dy * dy + dz * dz + dw * dw;
            dx = e2[j].x - xs[j].x; dy = e2[j].y - xs[j].y;
            dz = e2[j].z - xs[j].z; dw = e2[j].w - xs[j].w;
            d2 += dx * dx + dy * dy + dz * dz + dw * dw;
        }
        #pragma unroll
        for (int off = 4; off; off >>= 1) {
            d1 += __shfl_xor(d1, off, 8);
            d2 += __shfl_xor(d2, off, 8);
        }
        bool w2 = (d2 < d1) || (d2 == d1 && c2 < c1);
        float bd = w2 ? d2 : d1;
        float4* dst = (float4*)(outq + row * D + l8 * 16);
        #pragma unroll
        for (int j = 0; j < 4; ++j) dst[j] = w2 ? e2[j] : e1[j];
        if (l8 == 0) lacc += bd;
    }
    #pragma unroll
    for (int off = 32; off; off >>= 1) lacc += __shfl_down(lacc, off, 64);
    if (lane == 0) lsum[wave] = lacc;
    __syncthreads();
    if (t == 0) atomicAdd(loss_slot, 1.5f * ((lsum[0] + lsum[1]) + (lsum[2] + lsum[3])));
}

extern "C" void kernel_launch(void* const* d_in, const int* in_sizes, int n_in,
                              void* d_out, int out_size, void* d_ws, size_t ws_size,
                              hipStream_t stream) {
    const float* x   = (const float*)d_in[0];   // [32768,128]
    const float* emb = (const float*)d_in[1];   // [1024,128]
    float* outq      = (float*)d_out;
    float* loss_slot = outq + (size_t)N_ROWS * D;

    char* ws = (char*)d_ws;
    short8* Ehi   = (short8*)(ws + WS_EHI);
    short8* Elo   = (short8*)(ws + WS_ELO);
    float* en1024 = (float*)(ws + WS_EN);

    vq_prep<<<64, 256, 0, stream>>>(emb, Ehi, Elo, en1024, loss_slot);
    vq_main<<<256, 256, 0, stream>>>(x, (const int4*)Ehi, (const int4*)Elo,
                                     en1024, emb, outq, loss_slot);
}